// Round 9
// baseline (909.505 us; speedup 1.0000x reference)
//
#include <hip/hip_runtime.h>

#define SEQ   512
#define IN    28
#define HID   128
#define NCLS  10
#define MB    16       // batch rows per block -> 32 blocks
#define RP    136      // LDS row pitch in bf16 elems (272 B = 17*16B: aligned, conflict-free)

typedef __attribute__((ext_vector_type(8))) short short8v;   // 8 bf16 = 4 VGPR (guide §3)
typedef __attribute__((ext_vector_type(4))) float f32x4;

__device__ __forceinline__ unsigned short f2bf(float f) {
    unsigned int u = __float_as_uint(f);
    return (unsigned short)((u + 0x7FFFu + ((u >> 16) & 1u)) >> 16);   // RNE
}
__device__ __forceinline__ float bf2f(unsigned short h) {
    return __uint_as_float(((unsigned int)h) << 16);
}
__device__ __forceinline__ void split2(float f, unsigned short& hi, unsigned short& lo) {
    hi = f2bf(f);
    lo = f2bf(f - bf2f(hi));
}
__device__ __forceinline__ float fast_tanh(float x) {
    float e = __expf(2.0f * x);
    return 1.0f - 2.0f * __builtin_amdgcn_rcpf(e + 1.0f);
}
__device__ __forceinline__ f32x4 mfma16(short8v a, short8v b, f32x4 c) {
    return __builtin_amdgcn_mfma_f32_16x16x32_bf16(a, b, c, 0, 0, 0);
}

__global__ __launch_bounds__(256)
void rnn2_mfma(const float* __restrict__ x,
               const float* __restrict__ W_ih0, const float* __restrict__ W_hh0,
               const float* __restrict__ b_ih0, const float* __restrict__ b_hh0,
               const float* __restrict__ W_ih1, const float* __restrict__ W_hh1,
               const float* __restrict__ b_ih1, const float* __restrict__ b_hh1,
               const float* __restrict__ W_fc,  const float* __restrict__ b_fc,
               float* __restrict__ out)
{
    // LDS: [buf][arr: 0=h0hi 1=h0lo 2=h1hi 3=h1lo][MB][RP] bf16 bits
    __shared__ unsigned short lds[2][4][MB * RP];

    const int t    = threadIdx.x;
    const int lane = t & 63;
    const int w    = t >> 6;        // wave 0..3 owns units [32w, 32w+32)
    const int lm   = lane & 15;     // A-row m / B-col n
    const int lg   = lane >> 4;     // k-group (8 elems each)
    const int b0   = blockIdx.x * MB;

    // ---- persistent B-fragments (weights), hi/lo split. B[k][n]: n=lane&15, k=8*lg+e (+32*kt)
    short8v Bhh0h[2][4], Bhh0l[2][4];
    short8v Bih0h[2],    Bih0l[2];
    short8v Bih1h[2][4], Bih1l[2][4];
    short8v Bhh1h[2][4], Bhh1l[2][4];
    float bias0v[2], bias1v[2];

    #pragma unroll
    for (int nt = 0; nt < 2; ++nt) {
        const int j = 32 * w + 16 * nt + lm;
        bias0v[nt] = b_ih0[j] + b_hh0[j];
        bias1v[nt] = b_ih1[j] + b_hh1[j];
        #pragma unroll
        for (int kt = 0; kt < 4; ++kt) {
            const int kb = 32 * kt + 8 * lg;
            #pragma unroll
            for (int e = 0; e < 8; ++e) {
                unsigned short hh, hl;
                split2(W_hh0[j * HID + kb + e], hh, hl);
                Bhh0h[nt][kt][e] = (short)hh; Bhh0l[nt][kt][e] = (short)hl;
                split2(W_ih1[j * HID + kb + e], hh, hl);
                Bih1h[nt][kt][e] = (short)hh; Bih1l[nt][kt][e] = (short)hl;
                split2(W_hh1[j * HID + kb + e], hh, hl);
                Bhh1h[nt][kt][e] = (short)hh; Bhh1l[nt][kt][e] = (short)hl;
            }
        }
        const int kb2 = 8 * lg;
        #pragma unroll
        for (int e = 0; e < 8; ++e) {
            float f = (kb2 + e < IN) ? W_ih0[j * IN + kb2 + e] : 0.0f;
            unsigned short hh, hl;
            split2(f, hh, hl);
            Bih0h[nt][e] = (short)hh; Bih0l[nt][e] = (short)hl;
        }
    }

    // ---- zero LDS buf0 (h(-1)=0); buf1 too (cheap, one-time)
    {
        unsigned int* z = (unsigned int*)&lds[0][0][0];
        for (int i = t; i < (int)(sizeof(lds) / 4); i += 256) z[i] = 0u;
    }

    // ---- x loader: lane covers row lm, k=8*lg..8*lg+7 (group 3: k 24..27 + zeros)
    const float* xp = x + ((size_t)(b0 + lm) * SEQ) * IN + 8 * lg;
    float4 xf0, xf1;
    {
        xf0 = *(const float4*)xp;
        xf1 = (lg < 3) ? *(const float4*)(xp + 4) : make_float4(0.f, 0.f, 0.f, 0.f);
    }
    __syncthreads();

    // ---- pipelined time loop (R6-verified): iter it computes h0(it) and h1(it-1); 1 barrier.
    for (int it = 0; it <= SEQ; ++it) {
        const int rd = it & 1, wr = rd ^ 1;

        // A-fragments of h0(it-1), h1(it-2) from LDS buf[rd]; A[m][k]: m=lm, k=32*kt+8*lg+e
        short8v Ah0h[4], Ah0l[4], Ah1h[4], Ah1l[4];
        {
            const unsigned short* p0h = &lds[rd][0][lm * RP + 8 * lg];
            const unsigned short* p0l = &lds[rd][1][lm * RP + 8 * lg];
            const unsigned short* p1h = &lds[rd][2][lm * RP + 8 * lg];
            const unsigned short* p1l = &lds[rd][3][lm * RP + 8 * lg];
            #pragma unroll
            for (int kt = 0; kt < 4; ++kt) {
                Ah0h[kt] = *(const short8v*)(p0h + 32 * kt);
                Ah0l[kt] = *(const short8v*)(p0l + 32 * kt);
                Ah1h[kt] = *(const short8v*)(p1h + 32 * kt);
                Ah1l[kt] = *(const short8v*)(p1l + 32 * kt);
            }
        }

        // x A-fragment for t = min(it, SEQ-1)
        short8v Axh, Axl;
        {
            unsigned short hh, hl;
            split2(xf0.x, hh, hl); Axh[0] = (short)hh; Axl[0] = (short)hl;
            split2(xf0.y, hh, hl); Axh[1] = (short)hh; Axl[1] = (short)hl;
            split2(xf0.z, hh, hl); Axh[2] = (short)hh; Axl[2] = (short)hl;
            split2(xf0.w, hh, hl); Axh[3] = (short)hh; Axl[3] = (short)hl;
            split2(xf1.x, hh, hl); Axh[4] = (short)hh; Axl[4] = (short)hl;
            split2(xf1.y, hh, hl); Axh[5] = (short)hh; Axl[5] = (short)hl;
            split2(xf1.z, hh, hl); Axh[6] = (short)hh; Axl[6] = (short)hl;
            split2(xf1.w, hh, hl); Axh[7] = (short)hh; Axl[7] = (short)hl;
        }
        // prefetch x(it+1), clamped
        {
            const int tn = (it < SEQ - 1) ? it + 1 : SEQ - 1;
            const float* p = xp + tn * IN;
            xf0 = *(const float4*)p;
            xf1 = (lg < 3) ? *(const float4*)(p + 4) : make_float4(0.f, 0.f, 0.f, 0.f);
        }

        // ---- MFMA: GEMM1 = Wih0*x + Whh0*h0_prev ; GEMM2 = Wih1*h0_prev + Whh1*h1_prev2
        f32x4 acc0[2], acc1[2];
        #pragma unroll
        for (int nt = 0; nt < 2; ++nt) {
            f32x4 a = {0.f, 0.f, 0.f, 0.f};
            #pragma unroll
            for (int kt = 0; kt < 4; ++kt) {
                a = mfma16(Ah0h[kt], Bhh0h[nt][kt], a);
                a = mfma16(Ah0l[kt], Bhh0h[nt][kt], a);
                a = mfma16(Ah0h[kt], Bhh0l[nt][kt], a);
            }
            a = mfma16(Axh, Bih0h[nt], a);
            a = mfma16(Axl, Bih0h[nt], a);
            a = mfma16(Axh, Bih0l[nt], a);
            acc0[nt] = a;

            f32x4 c = {0.f, 0.f, 0.f, 0.f};
            #pragma unroll
            for (int kt = 0; kt < 4; ++kt) {
                c = mfma16(Ah0h[kt], Bih1h[nt][kt], c);
                c = mfma16(Ah0l[kt], Bih1h[nt][kt], c);
                c = mfma16(Ah0h[kt], Bih1l[nt][kt], c);
                c = mfma16(Ah1h[kt], Bhh1h[nt][kt], c);
                c = mfma16(Ah1l[kt], Bhh1h[nt][kt], c);
                c = mfma16(Ah1h[kt], Bhh1l[nt][kt], c);
            }
            acc1[nt] = c;
        }

        // ---- epilogue: C/D layout col=lane&15 (=unit j), row m=(lane>>4)*4+reg (m89-verified)
        #pragma unroll
        for (int nt = 0; nt < 2; ++nt) {
            const int j = 32 * w + 16 * nt + lm;
            #pragma unroll
            for (int r = 0; r < 4; ++r) {
                const int m = 4 * lg + r;
                unsigned short hh, hl;
                split2(fast_tanh(acc0[nt][r] + bias0v[nt]), hh, hl);
                lds[wr][0][m * RP + j] = hh;
                lds[wr][1][m * RP + j] = hl;
                unsigned short gh, gl;
                if (it == 0) { gh = 0; gl = 0; }
                else { split2(fast_tanh(acc1[nt][r] + bias1v[nt]), gh, gl); }
                lds[wr][2][m * RP + j] = gh;
                lds[wr][3][m * RP + j] = gl;
            }
        }
        __syncthreads();
    }

    // ---- fc: it=SEQ wrote h1(511) into buf[1]
    if (t < MB * NCLS) {
        const int r = t / NCLS, c = t % NCLS;
        float acc = b_fc[c];
        const unsigned short* hh = &lds[1][2][r * RP];
        const unsigned short* hl = &lds[1][3][r * RP];
        #pragma unroll 4
        for (int k = 0; k < HID; ++k)
            acc = fmaf(W_fc[c * HID + k], bf2f(hh[k]) + bf2f(hl[k]), acc);
        out[(b0 + r) * NCLS + c] = acc;
    }
}

extern "C" void kernel_launch(void* const* d_in, const int* in_sizes, int n_in,
                              void* d_out, int out_size, void* d_ws, size_t ws_size,
                              hipStream_t stream) {
    const float* x     = (const float*)d_in[0];
    const float* W_ih0 = (const float*)d_in[1];
    const float* W_hh0 = (const float*)d_in[2];
    const float* b_ih0 = (const float*)d_in[3];
    const float* b_hh0 = (const float*)d_in[4];
    const float* W_ih1 = (const float*)d_in[5];
    const float* W_hh1 = (const float*)d_in[6];
    const float* b_ih1 = (const float*)d_in[7];
    const float* b_hh1 = (const float*)d_in[8];
    const float* W_fc  = (const float*)d_in[9];
    const float* b_fc  = (const float*)d_in[10];
    float* out = (float*)d_out;

    rnn2_mfma<<<dim3(512 / MB), dim3(256), 0, stream>>>(
        x, W_ih0, W_hh0, b_ih0, b_hh0, W_ih1, W_hh1, b_ih1, b_hh1, W_fc, b_fc, out);
}

// Round 10
// 656.415 us; speedup vs baseline: 1.3856x; 1.3856x over previous
//
#include <hip/hip_runtime.h>

#define SEQ   512
#define IN    28
#define HID   128
#define NCLS  10
#define MB    16       // batch rows per block -> 32 blocks
#define RP    136      // LDS row pitch in bf16 elems (272 B, 16B-aligned)

typedef __attribute__((ext_vector_type(8))) short short8v;   // 8 bf16 = 4 VGPR
typedef __attribute__((ext_vector_type(4))) float f32x4;

__device__ __forceinline__ unsigned cvtpk(float a, float b) {
    unsigned r;
    asm("v_cvt_pk_bf16_f32 %0, %1, %2" : "=v"(r) : "v"(a), "v"(b));
    return r;   // low16 = bf16(a), high16 = bf16(b)
}
__device__ __forceinline__ unsigned short f2bf(float f) {
    unsigned int u = __float_as_uint(f);
    return (unsigned short)((u + 0x7FFFu + ((u >> 16) & 1u)) >> 16);   // RNE (init only)
}
__device__ __forceinline__ float bf2f(unsigned short h) {
    return __uint_as_float(((unsigned int)h) << 16);
}
__device__ __forceinline__ void split2(float f, unsigned short& hi, unsigned short& lo) {
    hi = f2bf(f);
    lo = f2bf(f - bf2f(hi));
}
__device__ __forceinline__ float fast_tanh(float x) {
    float e = __expf(2.0f * x);
    return 1.0f - 2.0f * __builtin_amdgcn_rcpf(e + 1.0f);
}
__device__ __forceinline__ f32x4 mfma16(short8v a, short8v b, f32x4 c) {
    return __builtin_amdgcn_mfma_f32_16x16x32_bf16(a, b, c, 0, 0, 0);
}

__global__ __launch_bounds__(512)
void rnn2_mfma(const float* __restrict__ x,
               const float* __restrict__ W_ih0, const float* __restrict__ W_hh0,
               const float* __restrict__ b_ih0, const float* __restrict__ b_hh0,
               const float* __restrict__ W_ih1, const float* __restrict__ W_hh1,
               const float* __restrict__ b_ih1, const float* __restrict__ b_hh1,
               const float* __restrict__ W_fc,  const float* __restrict__ b_fc,
               float* __restrict__ out)
{
    // LDS: [buf][arr: 0=h0hi 1=h0lo 2=h1hi 3=h1lo][MB*RP] bf16 bits
    __shared__ unsigned short lds[2][4][MB * RP];

    const int t    = threadIdx.x;   // 0..511
    const int lane = t & 63;
    const int w    = t >> 6;        // wave 0..7 owns units [16w, 16w+16)
    const int lm   = lane & 15;     // A row m (batch) / B col n (unit)
    const int lg   = lane >> 4;     // k-group (8 elems)
    const int b0   = blockIdx.x * MB;
    const int j    = 16 * w + lm;   // this lane's output unit

    // ---- persistent B-fragments (weights), hi/lo split. B[k][n]: n=lm, k=32*kt+8*lg+e
    short8v Bhh0h[4], Bhh0l[4], Bih1h[4], Bih1l[4], Bhh1h[4], Bhh1l[4];
    short8v Bih0h, Bih0l;
    #pragma unroll
    for (int kt = 0; kt < 4; ++kt) {
        const int kb = 32 * kt + 8 * lg;
        #pragma unroll
        for (int e = 0; e < 8; ++e) {
            unsigned short hh, hl;
            split2(W_hh0[j * HID + kb + e], hh, hl);
            Bhh0h[kt][e] = (short)hh; Bhh0l[kt][e] = (short)hl;
            split2(W_ih1[j * HID + kb + e], hh, hl);
            Bih1h[kt][e] = (short)hh; Bih1l[kt][e] = (short)hl;
            split2(W_hh1[j * HID + kb + e], hh, hl);
            Bhh1h[kt][e] = (short)hh; Bhh1l[kt][e] = (short)hl;
        }
    }
    {
        const int kb = 8 * lg;
        #pragma unroll
        for (int e = 0; e < 8; ++e) {
            float f = (kb + e < IN) ? W_ih0[j * IN + kb + e] : 0.0f;
            unsigned short hh, hl;
            split2(f, hh, hl);
            Bih0h[e] = (short)hh; Bih0l[e] = (short)hl;
        }
    }
    const float bias0 = b_ih0[j] + b_hh0[j];
    const float bias1 = b_ih1[j] + b_hh1[j];

    // ---- zero LDS (h(-1)=0 in both buffers)
    {
        unsigned int* z = (unsigned int*)&lds[0][0][0];
        for (int i = t; i < (int)(sizeof(lds) / 4); i += 512) z[i] = 0u;
    }

    // ---- x loader: lane covers row lm, k = 8lg..8lg+7 (lg==3: k 24..27 + zeros)
    const float* xp = x + ((size_t)(b0 + lm) * SEQ) * IN + 8 * lg;
    float4 xf0, xf1;
    xf0 = *(const float4*)xp;
    xf1 = (lg < 3) ? *(const float4*)(xp + 4) : make_float4(0.f, 0.f, 0.f, 0.f);
    __syncthreads();

    // ---- pipelined time loop: iter it computes h0(it) and h1(it-1); 1 barrier.
    for (int it = 0; it <= SEQ; ++it) {
        const int rd = it & 1, wr = rd ^ 1;

        // A-fragments of h0(it-1), h1(it-2) from LDS buf[rd]; A[m][k]: m=lm, k=32kt+8lg+e
        short8v Ah0h[4], Ah0l[4], Ah1h[4], Ah1l[4];
        {
            const unsigned short* p0h = &lds[rd][0][lm * RP + 8 * lg];
            const unsigned short* p0l = &lds[rd][1][lm * RP + 8 * lg];
            const unsigned short* p1h = &lds[rd][2][lm * RP + 8 * lg];
            const unsigned short* p1l = &lds[rd][3][lm * RP + 8 * lg];
            #pragma unroll
            for (int kt = 0; kt < 4; ++kt) {
                Ah0h[kt] = *(const short8v*)(p0h + 32 * kt);
                Ah0l[kt] = *(const short8v*)(p0l + 32 * kt);
                Ah1h[kt] = *(const short8v*)(p1h + 32 * kt);
                Ah1l[kt] = *(const short8v*)(p1l + 32 * kt);
            }
        }

        // x A-fragment (cvt_pk split: 4 pk for hi, unpack+sub+4 pk for lo)
        short8v Axh, Axl;
        {
            int4 hi, lo;
            hi.x = (int)cvtpk(xf0.x, xf0.y);
            hi.y = (int)cvtpk(xf0.z, xf0.w);
            hi.z = (int)cvtpk(xf1.x, xf1.y);
            hi.w = (int)cvtpk(xf1.z, xf1.w);
            lo.x = (int)cvtpk(xf0.x - __uint_as_float((unsigned)hi.x << 16),
                              xf0.y - __uint_as_float((unsigned)hi.x & 0xFFFF0000u));
            lo.y = (int)cvtpk(xf0.z - __uint_as_float((unsigned)hi.y << 16),
                              xf0.w - __uint_as_float((unsigned)hi.y & 0xFFFF0000u));
            lo.z = (int)cvtpk(xf1.x - __uint_as_float((unsigned)hi.z << 16),
                              xf1.y - __uint_as_float((unsigned)hi.z & 0xFFFF0000u));
            lo.w = (int)cvtpk(xf1.z - __uint_as_float((unsigned)hi.w << 16),
                              xf1.w - __uint_as_float((unsigned)hi.w & 0xFFFF0000u));
            Axh = *reinterpret_cast<short8v*>(&hi);
            Axl = *reinterpret_cast<short8v*>(&lo);
        }
        // prefetch x(it+1), clamped
        {
            const int tn = (it < SEQ - 1) ? it + 1 : SEQ - 1;
            const float* p = xp + tn * IN;
            xf0 = *(const float4*)p;
            xf1 = (lg < 3) ? *(const float4*)(p + 4) : make_float4(0.f, 0.f, 0.f, 0.f);
        }

        // ---- MFMA: 6 independent chains (term-class x layer), depth <= 8
        f32x4 hh0 = {0,0,0,0}, lh0 = {0,0,0,0}, hl0 = {0,0,0,0};
        f32x4 hh1 = {0,0,0,0}, lh1 = {0,0,0,0}, hl1 = {0,0,0,0};
        #pragma unroll
        for (int kt = 0; kt < 4; ++kt) {
            hh0 = mfma16(Ah0h[kt], Bhh0h[kt], hh0);
            lh0 = mfma16(Ah0l[kt], Bhh0h[kt], lh0);
            hl0 = mfma16(Ah0h[kt], Bhh0l[kt], hl0);
            hh1 = mfma16(Ah0h[kt], Bih1h[kt], hh1);
            lh1 = mfma16(Ah0l[kt], Bih1h[kt], lh1);
            hl1 = mfma16(Ah0h[kt], Bih1l[kt], hl1);
            hh1 = mfma16(Ah1h[kt], Bhh1h[kt], hh1);
            lh1 = mfma16(Ah1l[kt], Bhh1h[kt], lh1);
            hl1 = mfma16(Ah1h[kt], Bhh1l[kt], hl1);
        }
        hh0 = mfma16(Axh, Bih0h, hh0);
        lh0 = mfma16(Axl, Bih0h, lh0);
        hl0 = mfma16(Axh, Bih0l, hl0);

        f32x4 acc0, acc1;
        #pragma unroll
        for (int e = 0; e < 4; ++e) {
            acc0[e] = (hh0[e] + lh0[e]) + hl0[e];
            acc1[e] = (hh1[e] + lh1[e]) + hl1[e];
        }

        // ---- epilogue: C/D col=lm (unit j), row m=4lg+r (batch). cvt_pk splits.
        {
            float t0 = fast_tanh(acc0[0] + bias0);
            float t1 = fast_tanh(acc0[1] + bias0);
            float t2 = fast_tanh(acc0[2] + bias0);
            float t3 = fast_tanh(acc0[3] + bias0);
            unsigned h01 = cvtpk(t0, t1), h23 = cvtpk(t2, t3);
            unsigned l01 = cvtpk(t0 - __uint_as_float(h01 << 16),
                                 t1 - __uint_as_float(h01 & 0xFFFF0000u));
            unsigned l23 = cvtpk(t2 - __uint_as_float(h23 << 16),
                                 t3 - __uint_as_float(h23 & 0xFFFF0000u));
            const int m0 = 4 * lg;
            lds[wr][0][(m0 + 0) * RP + j] = (unsigned short)h01;
            lds[wr][0][(m0 + 1) * RP + j] = (unsigned short)(h01 >> 16);
            lds[wr][0][(m0 + 2) * RP + j] = (unsigned short)h23;
            lds[wr][0][(m0 + 3) * RP + j] = (unsigned short)(h23 >> 16);
            lds[wr][1][(m0 + 0) * RP + j] = (unsigned short)l01;
            lds[wr][1][(m0 + 1) * RP + j] = (unsigned short)(l01 >> 16);
            lds[wr][1][(m0 + 2) * RP + j] = (unsigned short)l23;
            lds[wr][1][(m0 + 3) * RP + j] = (unsigned short)(l23 >> 16);
        }
        {
            float t0, t1, t2, t3;
            if (it == 0) {
                t0 = t1 = t2 = t3 = 0.0f;
            } else {
                t0 = fast_tanh(acc1[0] + bias1);
                t1 = fast_tanh(acc1[1] + bias1);
                t2 = fast_tanh(acc1[2] + bias1);
                t3 = fast_tanh(acc1[3] + bias1);
            }
            unsigned h01 = cvtpk(t0, t1), h23 = cvtpk(t2, t3);
            unsigned l01 = cvtpk(t0 - __uint_as_float(h01 << 16),
                                 t1 - __uint_as_float(h01 & 0xFFFF0000u));
            unsigned l23 = cvtpk(t2 - __uint_as_float(h23 << 16),
                                 t3 - __uint_as_float(h23 & 0xFFFF0000u));
            const int m0 = 4 * lg;
            lds[wr][2][(m0 + 0) * RP + j] = (unsigned short)h01;
            lds[wr][2][(m0 + 1) * RP + j] = (unsigned short)(h01 >> 16);
            lds[wr][2][(m0 + 2) * RP + j] = (unsigned short)h23;
            lds[wr][2][(m0 + 3) * RP + j] = (unsigned short)(h23 >> 16);
            lds[wr][3][(m0 + 0) * RP + j] = (unsigned short)l01;
            lds[wr][3][(m0 + 1) * RP + j] = (unsigned short)(l01 >> 16);
            lds[wr][3][(m0 + 2) * RP + j] = (unsigned short)l23;
            lds[wr][3][(m0 + 3) * RP + j] = (unsigned short)(l23 >> 16);
        }
        __syncthreads();
    }

    // ---- fc: it=SEQ wrote h1(511) into buf[1]
    if (t < MB * NCLS) {
        const int r = t / NCLS, c = t % NCLS;
        float acc = b_fc[c];
        const unsigned short* hh = &lds[1][2][r * RP];
        const unsigned short* hl = &lds[1][3][r * RP];
        #pragma unroll 4
        for (int k = 0; k < HID; ++k)
            acc = fmaf(W_fc[c * HID + k], bf2f(hh[k]) + bf2f(hl[k]), acc);
        out[(b0 + r) * NCLS + c] = acc;
    }
}

extern "C" void kernel_launch(void* const* d_in, const int* in_sizes, int n_in,
                              void* d_out, int out_size, void* d_ws, size_t ws_size,
                              hipStream_t stream) {
    const float* x     = (const float*)d_in[0];
    const float* W_ih0 = (const float*)d_in[1];
    const float* W_hh0 = (const float*)d_in[2];
    const float* b_ih0 = (const float*)d_in[3];
    const float* b_hh0 = (const float*)d_in[4];
    const float* W_ih1 = (const float*)d_in[5];
    const float* W_hh1 = (const float*)d_in[6];
    const float* b_ih1 = (const float*)d_in[7];
    const float* b_hh1 = (const float*)d_in[8];
    const float* W_fc  = (const float*)d_in[9];
    const float* b_fc  = (const float*)d_in[10];
    float* out = (float*)d_out;

    rnn2_mfma<<<dim3(512 / MB), dim3(512), 0, stream>>>(
        x, W_ih0, W_hh0, b_ih0, b_hh0, W_ih1, W_hh1, b_ih1, b_hh1, W_fc, b_fc, out);
}

// Round 11
// 611.607 us; speedup vs baseline: 1.4871x; 1.0733x over previous
//
#include <hip/hip_runtime.h>

#define SEQ   512
#define IN    28
#define HID   128
#define NCLS  10
#define MB    16        // batch rows per block -> 32 blocks
#define PCH   144       // LDS pitch bytes for i8 h arrays (128 data + 16 pad)

typedef __attribute__((ext_vector_type(4))) int   i32x4;
typedef __attribute__((ext_vector_type(4))) float f32x4;
typedef __attribute__((ext_vector_type(8))) short short8v;

// h = a/127 + b/32512 ; W = wa/1024 + wb/262144
// aa products scale 1/(127*1024); cross (a*wb + b*wa) scale 1/(127*1024*256)
#define SH_AA (1.0f/130048.0f)

__device__ __forceinline__ unsigned short f2bf(float f) {
    unsigned u = __float_as_uint(f);
    return (unsigned short)((u + 0x7FFFu + ((u >> 16) & 1u)) >> 16);   // RNE
}
__device__ __forceinline__ float bf2f(unsigned short h) {
    return __uint_as_float(((unsigned)h) << 16);
}
__device__ __forceinline__ void split2(float f, unsigned short& hi, unsigned short& lo) {
    hi = f2bf(f);
    lo = f2bf(f - bf2f(hi));
}
__device__ __forceinline__ unsigned cvtpk(float a, float b) {
    unsigned r;
    asm("v_cvt_pk_bf16_f32 %0, %1, %2" : "=v"(r) : "v"(a), "v"(b));
    return r;   // lo16 = bf16(a), hi16 = bf16(b)
}
__device__ __forceinline__ float fast_tanh(float x) {
    float e = __expf(2.0f * x);
    return 1.0f - 2.0f * __builtin_amdgcn_rcpf(e + 1.0f);
}
__device__ __forceinline__ f32x4 mfma_bf(short8v a, short8v b, f32x4 c) {
    return __builtin_amdgcn_mfma_f32_16x16x32_bf16(a, b, c, 0, 0, 0);
}
__device__ __forceinline__ i32x4 mfma_i8(i32x4 a, i32x4 b, i32x4 c) {
    return __builtin_amdgcn_mfma_i32_16x16x64_i8(a, b, c, 0, 0, 0);
}
__device__ __forceinline__ void quantW(float wv, signed char& qa, signed char& qb) {
    int a = (int)rintf(wv * 1024.0f);
    float r = fmaf((float)a, -1.0f / 1024.0f, wv);
    int b = (int)rintf(r * 262144.0f);
    b = b > 127 ? 127 : (b < -127 ? -127 : b);
    qa = (signed char)a;
    qb = (signed char)b;
}

union FragI8 { i32x4 v; signed char c[16]; };
union FragBF { short8v s; unsigned u[4]; };

__global__ __launch_bounds__(512, 2)
void rnn2_i8(const float* __restrict__ x,
             const float* __restrict__ W_ih0, const float* __restrict__ W_hh0,
             const float* __restrict__ b_ih0, const float* __restrict__ b_hh0,
             const float* __restrict__ W_ih1, const float* __restrict__ W_hh1,
             const float* __restrict__ b_ih1, const float* __restrict__ b_hh1,
             const float* __restrict__ W_fc,  const float* __restrict__ b_fc,
             float* __restrict__ out)
{
    // h state: [arr: 0=a0 1=b0 2=a1 3=b1][buf][batch row][PCH]  (i8, [batch][unit] row-major)
    __shared__ __attribute__((aligned(16))) signed char hmem[4][2][MB * PCH];

    const int t    = threadIdx.x;   // 0..511
    const int lane = t & 63;
    const int w    = t >> 6;        // wave 0..7 owns units [16w, 16w+16)
    const int lm   = lane & 15;     // A: m (unit-in-tile) / B: n (batch) / D: col n (batch)
    const int lg   = lane >> 4;     // k-group
    const int b0   = blockIdx.x * MB;
    const int j    = 16 * w + lm;   // this lane's A-row unit

    // ---- weight fragments (A-operand: A[m=lm][k=64kt+16lg+e]), i8 2-term
    i32x4 Whh0a[2], Whh0b[2], Wih1a[2], Wih1b[2], Whh1a[2], Whh1b[2];
    #pragma unroll
    for (int kt = 0; kt < 2; ++kt) {
        const float* p0 = W_hh0 + j * HID + 64 * kt + 16 * lg;
        const float* p1 = W_ih1 + j * HID + 64 * kt + 16 * lg;
        const float* p2 = W_hh1 + j * HID + 64 * kt + 16 * lg;
        FragI8 a0, q0, a1, q1, a2, q2;
        #pragma unroll
        for (int e = 0; e < 16; ++e) {
            quantW(p0[e], a0.c[e], q0.c[e]);
            quantW(p1[e], a1.c[e], q1.c[e]);
            quantW(p2[e], a2.c[e], q2.c[e]);
        }
        Whh0a[kt] = a0.v; Whh0b[kt] = q0.v;
        Wih1a[kt] = a1.v; Wih1b[kt] = q1.v;
        Whh1a[kt] = a2.v; Whh1b[kt] = q2.v;
    }
    // ---- W_ih0 bf16 hi/lo fragments (K=32 >= IN=28), k = 8lg+e
    short8v WxH, WxL;
    {
        FragBF H, L;
        #pragma unroll
        for (int p = 0; p < 4; ++p) {
            const int k0 = 8 * lg + 2 * p, k1 = k0 + 1;
            float w0 = (k0 < IN) ? W_ih0[j * IN + k0] : 0.0f;
            float w1 = (k1 < IN) ? W_ih0[j * IN + k1] : 0.0f;
            unsigned short h0s, l0s, h1s, l1s;
            split2(w0, h0s, l0s);
            split2(w1, h1s, l1s);
            H.u[p] = (unsigned)h0s | ((unsigned)h1s << 16);
            L.u[p] = (unsigned)l0s | ((unsigned)l1s << 16);
        }
        WxH = H.s; WxL = L.s;
    }
    // ---- biases for D rows: unit = 16w + 4lg + r
    float bias0v[4], bias1v[4];
    #pragma unroll
    for (int r = 0; r < 4; ++r) {
        const int u = 16 * w + 4 * lg + r;
        bias0v[r] = b_ih0[u] + b_hh0[u];
        bias1v[r] = b_ih1[u] + b_hh1[u];
    }

    // ---- zero LDS (h(-1)=0 both buffers)
    {
        int* z = (int*)&hmem[0][0][0];
        #pragma unroll
        for (int i = 0; i < (int)(sizeof(hmem) / 4) / 512; ++i)
            z[t + i * 512] = 0;
    }

    // ---- x: lane covers batch lm, k = 8lg..8lg+7 (lg==3: k 24..27 + zeros)
    const float* xp = x + ((size_t)(b0 + lm) * SEQ) * IN + 8 * lg;
    float4 xA = *(const float4*)xp;
    float4 xB = (lg < 3) ? *(const float4*)(xp + 4) : make_float4(0.f, 0.f, 0.f, 0.f);
    __syncthreads();

    const int rbase = lm * PCH + 16 * lg;            // B-frag read base
    const int wbase = lm * PCH + 16 * w + 4 * lg;    // D write base

    // ---- pipelined time loop (R6-verified): iter it computes h0(it) and h1(it-1); 1 barrier.
    for (int it = 0; it <= SEQ; ++it) {
        const int rd = it & 1, wr = rd ^ 1;

        // B-frags of h from LDS buf[rd]: B[k=64kt+16lg+e][n=lm]
        i32x4 Ba0[2], Bb0[2], Ba1[2], Bb1[2];
        #pragma unroll
        for (int kt = 0; kt < 2; ++kt) {
            Ba0[kt] = *(const i32x4*)&hmem[0][rd][rbase + 64 * kt];
            Bb0[kt] = *(const i32x4*)&hmem[1][rd][rbase + 64 * kt];
            Ba1[kt] = *(const i32x4*)&hmem[2][rd][rbase + 64 * kt];
            Bb1[kt] = *(const i32x4*)&hmem[3][rd][rbase + 64 * kt];
        }

        // x B-frag (bf16 hi/lo via cvt_pk)
        short8v BxH, BxL;
        {
            FragBF H, L;
            H.u[0] = cvtpk(xA.x, xA.y);
            H.u[1] = cvtpk(xA.z, xA.w);
            H.u[2] = cvtpk(xB.x, xB.y);
            H.u[3] = cvtpk(xB.z, xB.w);
            L.u[0] = cvtpk(xA.x - __uint_as_float(H.u[0] << 16),
                           xA.y - __uint_as_float(H.u[0] & 0xFFFF0000u));
            L.u[1] = cvtpk(xA.z - __uint_as_float(H.u[1] << 16),
                           xA.w - __uint_as_float(H.u[1] & 0xFFFF0000u));
            L.u[2] = cvtpk(xB.x - __uint_as_float(H.u[2] << 16),
                           xB.y - __uint_as_float(H.u[2] & 0xFFFF0000u));
            L.u[3] = cvtpk(xB.z - __uint_as_float(H.u[3] << 16),
                           xB.w - __uint_as_float(H.u[3] & 0xFFFF0000u));
            BxH = H.s; BxL = L.s;
        }
        // prefetch x(it+1), clamped
        {
            const int tn = (it < SEQ - 1) ? it + 1 : SEQ - 1;
            const float* p = xp + (size_t)tn * IN;
            float4 nA = *(const float4*)p;
            float4 nB = (lg < 3) ? *(const float4*)(p + 4) : make_float4(0.f, 0.f, 0.f, 0.f);
            xA = nA; xB = nB;
        }

        // ---- MFMAs: 3 bf16 (x) + 18 i8, in 6 independent chains (depth <= 4)
        const i32x4 z4 = {0, 0, 0, 0};
        f32x4 accx = {0.f, 0.f, 0.f, 0.f};
        accx = mfma_bf(WxH, BxH, accx);
        accx = mfma_bf(WxL, BxH, accx);
        accx = mfma_bf(WxH, BxL, accx);

        i32x4 aa0 = mfma_i8(Whh0a[0], Ba0[0], z4);
        aa0 = mfma_i8(Whh0a[1], Ba0[1], aa0);
        i32x4 cr0 = mfma_i8(Whh0a[0], Bb0[0], z4);
        cr0 = mfma_i8(Whh0a[1], Bb0[1], cr0);
        cr0 = mfma_i8(Whh0b[0], Ba0[0], cr0);
        cr0 = mfma_i8(Whh0b[1], Ba0[1], cr0);

        i32x4 aa1 = mfma_i8(Wih1a[0], Ba0[0], z4);
        aa1 = mfma_i8(Wih1a[1], Ba0[1], aa1);
        aa1 = mfma_i8(Whh1a[0], Ba1[0], aa1);
        aa1 = mfma_i8(Whh1a[1], Ba1[1], aa1);
        i32x4 cr1a = mfma_i8(Wih1a[0], Bb0[0], z4);
        cr1a = mfma_i8(Wih1a[1], Bb0[1], cr1a);
        cr1a = mfma_i8(Wih1b[0], Ba0[0], cr1a);
        cr1a = mfma_i8(Wih1b[1], Ba0[1], cr1a);
        i32x4 cr1b = mfma_i8(Whh1a[0], Bb1[0], z4);
        cr1b = mfma_i8(Whh1a[1], Bb1[1], cr1b);
        cr1b = mfma_i8(Whh1b[0], Ba1[0], cr1b);
        cr1b = mfma_i8(Whh1b[1], Ba1[1], cr1b);

        // ---- epilogue: D[m=unit 4lg+r][n=batch lm]; combine, tanh, re-quantize, pack
        float t0[4], t1[4];
        #pragma unroll
        for (int r = 0; r < 4; ++r) {
            float pre0 = accx[r] + bias0v[r]
                       + SH_AA * ((float)aa0[r] + (float)cr0[r] * (1.0f / 256.0f));
            t0[r] = fast_tanh(pre0);
            float pre1 = bias1v[r]
                       + SH_AA * ((float)aa1[r] + (float)(cr1a[r] + cr1b[r]) * (1.0f / 256.0f));
            t1[r] = (it == 0) ? 0.0f : fast_tanh(pre1);
        }
        unsigned pa0 = 0, pb0 = 0, pa1 = 0, pb1 = 0;
        #pragma unroll
        for (int r = 0; r < 4; ++r) {
            int a = (int)rintf(t0[r] * 127.0f);
            float rr = fmaf((float)a, -1.0f / 127.0f, t0[r]);
            int b = (int)rintf(rr * 32512.0f);
            b = b > 127 ? 127 : (b < -127 ? -127 : b);
            pa0 |= ((unsigned)(a & 255)) << (8 * r);
            pb0 |= ((unsigned)(b & 255)) << (8 * r);
            int a1i = (int)rintf(t1[r] * 127.0f);
            float r1 = fmaf((float)a1i, -1.0f / 127.0f, t1[r]);
            int b1i = (int)rintf(r1 * 32512.0f);
            b1i = b1i > 127 ? 127 : (b1i < -127 ? -127 : b1i);
            pa1 |= ((unsigned)(a1i & 255)) << (8 * r);
            pb1 |= ((unsigned)(b1i & 255)) << (8 * r);
        }
        *(unsigned*)&hmem[0][wr][wbase] = pa0;
        *(unsigned*)&hmem[1][wr][wbase] = pb0;
        *(unsigned*)&hmem[2][wr][wbase] = pa1;
        *(unsigned*)&hmem[3][wr][wbase] = pb1;
        __syncthreads();
    }

    // ---- fc: it=SEQ wrote h1(511) into buf 1 of arrays a1/b1
    if (t < MB * NCLS) {
        const int r = t / NCLS, c = t % NCLS;
        float acc = b_fc[c];
        const signed char* pa = &hmem[2][1][r * PCH];
        const signed char* pb = &hmem[3][1][r * PCH];
        #pragma unroll 4
        for (int k = 0; k < HID; ++k) {
            float h = (float)pa[k] * (1.0f / 127.0f) + (float)pb[k] * (1.0f / 32512.0f);
            acc = fmaf(W_fc[c * HID + k], h, acc);
        }
        out[(b0 + r) * NCLS + c] = acc;
    }
}

extern "C" void kernel_launch(void* const* d_in, const int* in_sizes, int n_in,
                              void* d_out, int out_size, void* d_ws, size_t ws_size,
                              hipStream_t stream) {
    const float* x     = (const float*)d_in[0];
    const float* W_ih0 = (const float*)d_in[1];
    const float* W_hh0 = (const float*)d_in[2];
    const float* b_ih0 = (const float*)d_in[3];
    const float* b_hh0 = (const float*)d_in[4];
    const float* W_ih1 = (const float*)d_in[5];
    const float* W_hh1 = (const float*)d_in[6];
    const float* b_ih1 = (const float*)d_in[7];
    const float* b_hh1 = (const float*)d_in[8];
    const float* W_fc  = (const float*)d_in[9];
    const float* b_fc  = (const float*)d_in[10];
    float* out = (float*)d_out;

    rnn2_i8<<<dim3(512 / MB), dim3(512), 0, stream>>>(
        x, W_ih0, W_hh0, b_ih0, b_hh0, W_ih1, W_hh1, b_ih1, b_hh1, W_fc, b_fc, out);
}

// Round 12
// 496.954 us; speedup vs baseline: 1.8302x; 1.2307x over previous
//
#include <hip/hip_runtime.h>

#define SEQ   512
#define IN    28
#define HID   128
#define NCLS  10
#define MB    16        // batch rows per block -> 32 blocks
#define PCH   144       // LDS pitch bytes for i8 h arrays (128 data + 16 pad)
#define MAGICF 12582912.0f   // 1.5 * 2^23

typedef __attribute__((ext_vector_type(4))) int   i32x4;
typedef __attribute__((ext_vector_type(4))) float f32x4;
typedef __attribute__((ext_vector_type(8))) short short8v;

// h = a/127 + b/32512 ; W = wa/1024 + wb/262144
// a*wa scale 1/(127*1024)=SH_AA; cross (a*wb + b*wa) scale SH_AA/256
#define SH_AA (1.0f/130048.0f)

__device__ __forceinline__ unsigned short f2bf(float f) {
    unsigned u = __float_as_uint(f);
    return (unsigned short)((u + 0x7FFFu + ((u >> 16) & 1u)) >> 16);   // RNE
}
__device__ __forceinline__ float bf2f(unsigned short h) {
    return __uint_as_float(((unsigned)h) << 16);
}
__device__ __forceinline__ void split2(float f, unsigned short& hi, unsigned short& lo) {
    hi = f2bf(f);
    lo = f2bf(f - bf2f(hi));
}
__device__ __forceinline__ unsigned cvtpk(float a, float b) {
    unsigned r;
    asm("v_cvt_pk_bf16_f32 %0, %1, %2" : "=v"(r) : "v"(a), "v"(b));
    return r;
}
__device__ __forceinline__ float fast_tanh(float x) {
    float e = __expf(2.0f * x);
    return 1.0f - 2.0f * __builtin_amdgcn_rcpf(e + 1.0f);
}
__device__ __forceinline__ f32x4 mfma_bf(short8v a, short8v b, f32x4 c) {
    return __builtin_amdgcn_mfma_f32_16x16x32_bf16(a, b, c, 0, 0, 0);
}
__device__ __forceinline__ i32x4 mfma_i8(i32x4 a, i32x4 b, i32x4 c) {
    return __builtin_amdgcn_mfma_i32_16x16x64_i8(a, b, c, 0, 0, 0);
}
__device__ __forceinline__ void quantW(float wv, signed char& qa, signed char& qb) {
    int a = (int)rintf(wv * 1024.0f);
    float r = fmaf((float)a, -1.0f / 1024.0f, wv);
    int b = (int)rintf(r * 262144.0f);
    b = b > 127 ? 127 : (b < -127 ? -127 : b);
    qa = (signed char)a;
    qb = (signed char)b;
}
// magic-number 2-term quantize of 4 tanh outputs -> packed a-bytes, b-bytes
__device__ __forceinline__ void quant4(const float t0, const float t1,
                                       const float t2, const float t3,
                                       unsigned& pa, unsigned& pb) {
    float f1a = fmaf(t0, 127.0f, MAGICF), f1b = fmaf(t1, 127.0f, MAGICF);
    float f1c = fmaf(t2, 127.0f, MAGICF), f1d = fmaf(t3, 127.0f, MAGICF);
    float r0 = fmaf(f1a - MAGICF, -1.0f / 127.0f, t0);
    float r1 = fmaf(f1b - MAGICF, -1.0f / 127.0f, t1);
    float r2 = fmaf(f1c - MAGICF, -1.0f / 127.0f, t2);
    float r3 = fmaf(f1d - MAGICF, -1.0f / 127.0f, t3);
    float f2a = fminf(fmaf(r0, 32512.0f, MAGICF), MAGICF + 127.0f);
    float f2b = fminf(fmaf(r1, 32512.0f, MAGICF), MAGICF + 127.0f);
    float f2c = fminf(fmaf(r2, 32512.0f, MAGICF), MAGICF + 127.0f);
    float f2d = fminf(fmaf(r3, 32512.0f, MAGICF), MAGICF + 127.0f);
    pa = (__float_as_uint(f1a) & 0xFFu)        | ((__float_as_uint(f1b) & 0xFFu) << 8)
       | ((__float_as_uint(f1c) & 0xFFu) << 16) | ((__float_as_uint(f1d) & 0xFFu) << 24);
    pb = (__float_as_uint(f2a) & 0xFFu)        | ((__float_as_uint(f2b) & 0xFFu) << 8)
       | ((__float_as_uint(f2c) & 0xFFu) << 16) | ((__float_as_uint(f2d) & 0xFFu) << 24);
}

union FragI8 { i32x4 v; signed char c[16]; };
union FragBF { short8v s; unsigned u[4]; };

__global__ __launch_bounds__(768)
void rnn2_i8s(const float* __restrict__ x,
              const float* __restrict__ W_ih0, const float* __restrict__ W_hh0,
              const float* __restrict__ b_ih0, const float* __restrict__ b_hh0,
              const float* __restrict__ W_ih1, const float* __restrict__ W_hh1,
              const float* __restrict__ b_ih1, const float* __restrict__ b_hh1,
              const float* __restrict__ W_fc,  const float* __restrict__ b_fc,
              float* __restrict__ out)
{
    // h state: [arr: 0=a0 1=b0 2=a1 3=b1][buf][batch row * PCH] (i8, [batch][unit])
    __shared__ __attribute__((aligned(16))) signed char hmem[4][2][MB * PCH];

    const int t    = threadIdx.x;   // 0..767 (12 waves)
    const int lane = t & 63;
    const int w    = t >> 6;        // waves 0-7: L0 role; waves 8-11: L1 role (2 tiles)
    const int lm   = lane & 15;
    const int lg   = lane >> 4;
    const int b0   = blockIdx.x * MB;
    const bool isL0 = (w < 8);

    // ---- role-specific persistent weight fragments
    i32x4 Whh0a[2], Whh0b[2];            // L0
    short8v WxH = {}, WxL = {};          // L0
    float bias0v[4] = {0, 0, 0, 0};      // L0
    i32x4 W1a[2][2], W1b[2][2];          // L1: W_ih1 [tile][kt]
    i32x4 W2a[2][2], W2b[2][2];          // L1: W_hh1 [tile][kt]
    float bias1v[2][4];                  // L1 [tile][r]

    if (isL0) {
        const int j = 16 * w + lm;       // A-row unit for tile w
        #pragma unroll
        for (int kt = 0; kt < 2; ++kt) {
            const float* p = W_hh0 + j * HID + 64 * kt + 16 * lg;
            FragI8 a, b;
            #pragma unroll
            for (int e = 0; e < 16; ++e) quantW(p[e], a.c[e], b.c[e]);
            Whh0a[kt] = a.v; Whh0b[kt] = b.v;
        }
        FragBF H, L;
        #pragma unroll
        for (int p = 0; p < 4; ++p) {
            const int k0 = 8 * lg + 2 * p, k1 = k0 + 1;
            float w0 = (k0 < IN) ? W_ih0[j * IN + k0] : 0.0f;
            float w1 = (k1 < IN) ? W_ih0[j * IN + k1] : 0.0f;
            unsigned short h0s, l0s, h1s, l1s;
            split2(w0, h0s, l0s);
            split2(w1, h1s, l1s);
            H.u[p] = (unsigned)h0s | ((unsigned)h1s << 16);
            L.u[p] = (unsigned)l0s | ((unsigned)l1s << 16);
        }
        WxH = H.s; WxL = L.s;
        #pragma unroll
        for (int r = 0; r < 4; ++r) {
            const int u = 16 * w + 4 * lg + r;
            bias0v[r] = b_ih0[u] + b_hh0[u];
        }
    } else {
        const int w1 = w - 8;
        #pragma unroll
        for (int tile = 0; tile < 2; ++tile) {
            const int T = 2 * w1 + tile;
            const int j = 16 * T + lm;
            #pragma unroll
            for (int kt = 0; kt < 2; ++kt) {
                const float* p1 = W_ih1 + j * HID + 64 * kt + 16 * lg;
                const float* p2 = W_hh1 + j * HID + 64 * kt + 16 * lg;
                FragI8 a1, q1, a2, q2;
                #pragma unroll
                for (int e = 0; e < 16; ++e) {
                    quantW(p1[e], a1.c[e], q1.c[e]);
                    quantW(p2[e], a2.c[e], q2.c[e]);
                }
                W1a[tile][kt] = a1.v; W1b[tile][kt] = q1.v;
                W2a[tile][kt] = a2.v; W2b[tile][kt] = q2.v;
            }
            #pragma unroll
            for (int r = 0; r < 4; ++r) {
                const int u = 16 * T + 4 * lg + r;
                bias1v[tile][r] = b_ih1[u] + b_hh1[u];
            }
        }
    }

    // ---- zero LDS (h(-1)=0 both buffers): 4608 dwords / 768 threads = 6 each
    {
        int* z = (int*)&hmem[0][0][0];
        #pragma unroll
        for (int i = 0; i < 6; ++i) z[t + i * 768] = 0;
    }

    // ---- x (L0 waves only): lane covers batch lm, k = 8lg..8lg+7
    const float* xp = x + ((size_t)(b0 + lm) * SEQ) * IN + 8 * lg;
    float4 xA = make_float4(0.f, 0.f, 0.f, 0.f), xB = xA;
    if (isL0) {
        xA = *(const float4*)xp;
        if (lg < 3) xB = *(const float4*)(xp + 4);
    }
    __syncthreads();

    const int rbase = lm * PCH + 16 * lg;
    const i32x4 z4 = {0, 0, 0, 0};

    // ---- pipelined time loop: iter it computes h0(it) [L0 waves] and h1(it-1) [L1 waves]
    for (int it = 0; it <= SEQ; ++it) {
        const int rd = it & 1, wr = rd ^ 1;

        if (isL0) {
            i32x4 Ba0[2], Bb0[2];
            #pragma unroll
            for (int kt = 0; kt < 2; ++kt) {
                Ba0[kt] = *(const i32x4*)&hmem[0][rd][rbase + 64 * kt];
                Bb0[kt] = *(const i32x4*)&hmem[1][rd][rbase + 64 * kt];
            }
            // x B-frag (bf16 hi/lo via cvt_pk)
            short8v BxH, BxL;
            {
                FragBF H, L;
                H.u[0] = cvtpk(xA.x, xA.y);
                H.u[1] = cvtpk(xA.z, xA.w);
                H.u[2] = cvtpk(xB.x, xB.y);
                H.u[3] = cvtpk(xB.z, xB.w);
                L.u[0] = cvtpk(xA.x - __uint_as_float(H.u[0] << 16),
                               xA.y - __uint_as_float(H.u[0] & 0xFFFF0000u));
                L.u[1] = cvtpk(xA.z - __uint_as_float(H.u[1] << 16),
                               xA.w - __uint_as_float(H.u[1] & 0xFFFF0000u));
                L.u[2] = cvtpk(xB.x - __uint_as_float(H.u[2] << 16),
                               xB.y - __uint_as_float(H.u[2] & 0xFFFF0000u));
                L.u[3] = cvtpk(xB.z - __uint_as_float(H.u[3] << 16),
                               xB.w - __uint_as_float(H.u[3] & 0xFFFF0000u));
                BxH = H.s; BxL = L.s;
            }
            // prefetch x(it+1), clamped
            {
                const int tn = (it < SEQ - 1) ? it + 1 : SEQ - 1;
                const float* p = xp + (size_t)tn * IN;
                xA = *(const float4*)p;
                xB = (lg < 3) ? *(const float4*)(p + 4) : make_float4(0.f, 0.f, 0.f, 0.f);
            }

            f32x4 accx = {bias0v[0], bias0v[1], bias0v[2], bias0v[3]};
            accx = mfma_bf(WxH, BxH, accx);
            accx = mfma_bf(WxL, BxH, accx);
            accx = mfma_bf(WxH, BxL, accx);

            i32x4 aa0 = mfma_i8(Whh0a[0], Ba0[0], z4);
            aa0 = mfma_i8(Whh0a[1], Ba0[1], aa0);
            i32x4 cr0 = mfma_i8(Whh0a[0], Bb0[0], z4);
            cr0 = mfma_i8(Whh0a[1], Bb0[1], cr0);
            cr0 = mfma_i8(Whh0b[0], Ba0[0], cr0);
            cr0 = mfma_i8(Whh0b[1], Ba0[1], cr0);

            float t0 = fast_tanh(accx[0] + SH_AA * ((float)aa0[0] + (float)cr0[0] * (1.0f / 256.0f)));
            float t1 = fast_tanh(accx[1] + SH_AA * ((float)aa0[1] + (float)cr0[1] * (1.0f / 256.0f)));
            float t2 = fast_tanh(accx[2] + SH_AA * ((float)aa0[2] + (float)cr0[2] * (1.0f / 256.0f)));
            float t3 = fast_tanh(accx[3] + SH_AA * ((float)aa0[3] + (float)cr0[3] * (1.0f / 256.0f)));
            unsigned pa, pb;
            quant4(t0, t1, t2, t3, pa, pb);
            const int wb = lm * PCH + 16 * w + 4 * lg;
            *(unsigned*)&hmem[0][wr][wb] = pa;
            *(unsigned*)&hmem[1][wr][wb] = pb;
        } else {
            i32x4 Ba0[2], Bb0[2], Ba1[2], Bb1[2];
            #pragma unroll
            for (int kt = 0; kt < 2; ++kt) {
                Ba0[kt] = *(const i32x4*)&hmem[0][rd][rbase + 64 * kt];
                Bb0[kt] = *(const i32x4*)&hmem[1][rd][rbase + 64 * kt];
                Ba1[kt] = *(const i32x4*)&hmem[2][rd][rbase + 64 * kt];
                Bb1[kt] = *(const i32x4*)&hmem[3][rd][rbase + 64 * kt];
            }
            const int w1 = w - 8;
            #pragma unroll
            for (int tile = 0; tile < 2; ++tile) {
                i32x4 aa1 = mfma_i8(W1a[tile][0], Ba0[0], z4);
                aa1 = mfma_i8(W1a[tile][1], Ba0[1], aa1);
                aa1 = mfma_i8(W2a[tile][0], Ba1[0], aa1);
                aa1 = mfma_i8(W2a[tile][1], Ba1[1], aa1);
                i32x4 cra = mfma_i8(W1a[tile][0], Bb0[0], z4);
                cra = mfma_i8(W1a[tile][1], Bb0[1], cra);
                cra = mfma_i8(W1b[tile][0], Ba0[0], cra);
                cra = mfma_i8(W1b[tile][1], Ba0[1], cra);
                i32x4 crb = mfma_i8(W2a[tile][0], Bb1[0], z4);
                crb = mfma_i8(W2a[tile][1], Bb1[1], crb);
                crb = mfma_i8(W2b[tile][0], Ba1[0], crb);
                crb = mfma_i8(W2b[tile][1], Ba1[1], crb);

                float t0, t1, t2, t3;
                if (it == 0) {
                    t0 = t1 = t2 = t3 = 0.0f;
                } else {
                    t0 = fast_tanh(bias1v[tile][0] + SH_AA * ((float)aa1[0] + (float)(cra[0] + crb[0]) * (1.0f / 256.0f)));
                    t1 = fast_tanh(bias1v[tile][1] + SH_AA * ((float)aa1[1] + (float)(cra[1] + crb[1]) * (1.0f / 256.0f)));
                    t2 = fast_tanh(bias1v[tile][2] + SH_AA * ((float)aa1[2] + (float)(cra[2] + crb[2]) * (1.0f / 256.0f)));
                    t3 = fast_tanh(bias1v[tile][3] + SH_AA * ((float)aa1[3] + (float)(cra[3] + crb[3]) * (1.0f / 256.0f)));
                }
                unsigned pa, pb;
                quant4(t0, t1, t2, t3, pa, pb);
                const int T = 2 * w1 + tile;
                const int wb = lm * PCH + 16 * T + 4 * lg;
                *(unsigned*)&hmem[2][wr][wb] = pa;
                *(unsigned*)&hmem[3][wr][wb] = pb;
            }
        }
        __syncthreads();
    }

    // ---- fc: it=SEQ wrote h1(511) into buf 1 of arrays a1/b1
    if (t < MB * NCLS) {
        const int r = t / NCLS, c = t % NCLS;
        float acc = b_fc[c];
        const signed char* pa = &hmem[2][1][r * PCH];
        const signed char* pb = &hmem[3][1][r * PCH];
        #pragma unroll 4
        for (int k = 0; k < HID; ++k) {
            float h = (float)pa[k] * (1.0f / 127.0f) + (float)pb[k] * (1.0f / 32512.0f);
            acc = fmaf(W_fc[c * HID + k], h, acc);
        }
        out[(b0 + r) * NCLS + c] = acc;
    }
}

extern "C" void kernel_launch(void* const* d_in, const int* in_sizes, int n_in,
                              void* d_out, int out_size, void* d_ws, size_t ws_size,
                              hipStream_t stream) {
    const float* x     = (const float*)d_in[0];
    const float* W_ih0 = (const float*)d_in[1];
    const float* W_hh0 = (const float*)d_in[2];
    const float* b_ih0 = (const float*)d_in[3];
    const float* b_hh0 = (const float*)d_in[4];
    const float* W_ih1 = (const float*)d_in[5];
    const float* W_hh1 = (const float*)d_in[6];
    const float* b_ih1 = (const float*)d_in[7];
    const float* b_hh1 = (const float*)d_in[8];
    const float* W_fc  = (const float*)d_in[9];
    const float* b_fc  = (const float*)d_in[10];
    float* out = (float*)d_out;

    rnn2_i8s<<<dim3(512 / MB), dim3(768), 0, stream>>>(
        x, W_ih0, W_hh0, b_ih0, b_hh0, W_ih1, W_hh1, b_ih1, b_hh1, W_fc, b_fc, out);
}

// Round 13
// 329.672 us; speedup vs baseline: 2.7588x; 1.5074x over previous
//
#include <hip/hip_runtime.h>

#define SEQ   512
#define IN    28
#define HID   128
#define NCLS  10
#define MB    16        // batch rows per block -> 32 blocks
#define PCH   144       // LDS pitch bytes for i8 h arrays (16B-aligned; 2-way bank alias = free)
#define MAGICF 12582912.0f   // 1.5 * 2^23

typedef __attribute__((ext_vector_type(4))) int   i32x4;
typedef __attribute__((ext_vector_type(4))) float f32x4;
typedef __attribute__((ext_vector_type(8))) short short8v;

// h = a/127 ; W = wa/1024 + wb/262144
// wa*a scale 1/(127*1024)=SH_AA ; wb*a scale SH_AA/256
#define SH_AA (1.0f/130048.0f)

__device__ __forceinline__ unsigned short f2bf(float f) {
    unsigned u = __float_as_uint(f);
    return (unsigned short)((u + 0x7FFFu + ((u >> 16) & 1u)) >> 16);   // RNE
}
__device__ __forceinline__ float bf2f(unsigned short h) {
    return __uint_as_float(((unsigned)h) << 16);
}
__device__ __forceinline__ void split2(float f, unsigned short& hi, unsigned short& lo) {
    hi = f2bf(f);
    lo = f2bf(f - bf2f(hi));
}
__device__ __forceinline__ unsigned cvtpk(float a, float b) {
    unsigned r;
    asm("v_cvt_pk_bf16_f32 %0, %1, %2" : "=v"(r) : "v"(a), "v"(b));
    return r;
}
__device__ __forceinline__ float fast_tanh(float x) {
    float e = __expf(2.0f * x);
    return 1.0f - 2.0f * __builtin_amdgcn_rcpf(e + 1.0f);
}
__device__ __forceinline__ f32x4 mfma_bf(short8v a, short8v b, f32x4 c) {
    return __builtin_amdgcn_mfma_f32_16x16x32_bf16(a, b, c, 0, 0, 0);
}
__device__ __forceinline__ i32x4 mfma_i8(i32x4 a, i32x4 b, i32x4 c) {
    return __builtin_amdgcn_mfma_i32_16x16x64_i8(a, b, c, 0, 0, 0);
}
__device__ __forceinline__ void quantW(float wv, signed char& qa, signed char& qb) {
    int a = (int)rintf(wv * 1024.0f);
    float r = fmaf((float)a, -1.0f / 1024.0f, wv);
    int b = (int)rintf(r * 262144.0f);
    b = b > 127 ? 127 : (b < -127 ? -127 : b);
    qa = (signed char)a;
    qb = (signed char)b;
}
// 1-term magic quantize: 4 tanh outputs -> packed signed bytes (a = rne(t*127))
__device__ __forceinline__ unsigned quant4a(float t0, float t1, float t2, float t3) {
    unsigned u0 = __float_as_uint(fmaf(t0, 127.0f, MAGICF));
    unsigned u1 = __float_as_uint(fmaf(t1, 127.0f, MAGICF));
    unsigned u2 = __float_as_uint(fmaf(t2, 127.0f, MAGICF));
    unsigned u3 = __float_as_uint(fmaf(t3, 127.0f, MAGICF));
    return (u0 & 0xFFu) | ((u1 & 0xFFu) << 8) | ((u2 & 0xFFu) << 16) | ((u3 & 0xFFu) << 24);
}

union FragI8 { i32x4 v; signed char c[16]; };
union FragBF { short8v s; unsigned u[4]; };

__global__ __launch_bounds__(1024)
void rnn2_i8t(const float* __restrict__ x,
              const float* __restrict__ W_ih0, const float* __restrict__ W_hh0,
              const float* __restrict__ b_ih0, const float* __restrict__ b_hh0,
              const float* __restrict__ W_ih1, const float* __restrict__ W_hh1,
              const float* __restrict__ b_ih1, const float* __restrict__ b_hh1,
              const float* __restrict__ W_fc,  const float* __restrict__ b_fc,
              float* __restrict__ out)
{
    // h state: [arr: 0=h0 1=h1][buf][batch row * PCH] (i8 a-term, [batch][unit])
    __shared__ __attribute__((aligned(16))) signed char hmem[2][2][MB * PCH];
    __shared__ float hfin[MB][HID + 4];   // exact f32 h1(511) for the fc

    const int t    = threadIdx.x;   // 0..1023 (16 waves)
    const int lane = t & 63;
    const int w    = t >> 6;        // waves 0-7: L0 (tile w); waves 8-15: L1 (tile w-8)
    const int lm   = lane & 15;
    const int lg   = lane >> 4;
    const int b0   = blockIdx.x * MB;
    const bool isL0 = (w < 8);
    const int T    = isL0 ? w : (w - 8);   // 16-unit tile
    const int j    = 16 * T + lm;          // A-row unit for weight loading

    // ---- role-specific persistent weight fragments (A-operand: A[m][k=64kt+16lg+e])
    i32x4 Wa[2][2], Wb[2][2];      // L0: [0]=Whh0 ; L1: [0]=Wih1, [1]=Whh1
    short8v WxH = {}, WxL = {};    // L0 only
    float biasv[4];

    if (isL0) {
        #pragma unroll
        for (int kt = 0; kt < 2; ++kt) {
            const float* p = W_hh0 + j * HID + 64 * kt + 16 * lg;
            FragI8 a, b;
            #pragma unroll
            for (int e = 0; e < 16; ++e) quantW(p[e], a.c[e], b.c[e]);
            Wa[0][kt] = a.v; Wb[0][kt] = b.v;
        }
        FragBF H, L;
        #pragma unroll
        for (int p = 0; p < 4; ++p) {
            const int k0 = 8 * lg + 2 * p, k1 = k0 + 1;
            float w0 = (k0 < IN) ? W_ih0[j * IN + k0] : 0.0f;
            float w1 = (k1 < IN) ? W_ih0[j * IN + k1] : 0.0f;
            unsigned short h0s, l0s, h1s, l1s;
            split2(w0, h0s, l0s);
            split2(w1, h1s, l1s);
            H.u[p] = (unsigned)h0s | ((unsigned)h1s << 16);
            L.u[p] = (unsigned)l0s | ((unsigned)l1s << 16);
        }
        WxH = H.s; WxL = L.s;
        #pragma unroll
        for (int r = 0; r < 4; ++r) {
            const int u = 16 * T + 4 * lg + r;
            biasv[r] = b_ih0[u] + b_hh0[u];
        }
    } else {
        #pragma unroll
        for (int kt = 0; kt < 2; ++kt) {
            const float* p1 = W_ih1 + j * HID + 64 * kt + 16 * lg;
            const float* p2 = W_hh1 + j * HID + 64 * kt + 16 * lg;
            FragI8 a1, q1, a2, q2;
            #pragma unroll
            for (int e = 0; e < 16; ++e) {
                quantW(p1[e], a1.c[e], q1.c[e]);
                quantW(p2[e], a2.c[e], q2.c[e]);
            }
            Wa[0][kt] = a1.v; Wb[0][kt] = q1.v;
            Wa[1][kt] = a2.v; Wb[1][kt] = q2.v;
        }
        #pragma unroll
        for (int r = 0; r < 4; ++r) {
            const int u = 16 * T + 4 * lg + r;
            biasv[r] = b_ih1[u] + b_hh1[u];
        }
    }

    // ---- zero LDS h-state (both buffers): 2304 dwords / 1024 threads
    {
        int* z = (int*)&hmem[0][0][0];
        #pragma unroll
        for (int i = 0; i < 3; ++i) {
            const int idx = t + i * 1024;
            if (idx < (int)(sizeof(hmem) / 4)) z[idx] = 0;
        }
    }

    // ---- x (L0 waves only): lane covers batch lm, k = 8lg..8lg+7
    const float* xp = x + ((size_t)(b0 + lm) * SEQ) * IN + 8 * lg;
    float4 xA = make_float4(0.f, 0.f, 0.f, 0.f), xB = xA;
    if (isL0) {
        xA = *(const float4*)xp;
        if (lg < 3) xB = *(const float4*)(xp + 4);
    }
    __syncthreads();

    const int rbase = lm * PCH + 16 * lg;
    const int wbase = lm * PCH + 16 * T + 4 * lg;
    const i32x4 z4 = {0, 0, 0, 0};

    // ---- pipelined time loop: iter it computes h0(it) [L0] and h1(it-1) [L1]; 1 barrier.
    for (int it = 0; it <= SEQ; ++it) {
        const int rd = it & 1, wr = rd ^ 1;

        if (isL0) {
            i32x4 Ba0[2];
            Ba0[0] = *(const i32x4*)&hmem[0][rd][rbase];
            Ba0[1] = *(const i32x4*)&hmem[0][rd][rbase + 64];

            // x B-frag (bf16 hi/lo via cvt_pk)
            short8v BxH, BxL;
            {
                FragBF H, L;
                H.u[0] = cvtpk(xA.x, xA.y);
                H.u[1] = cvtpk(xA.z, xA.w);
                H.u[2] = cvtpk(xB.x, xB.y);
                H.u[3] = cvtpk(xB.z, xB.w);
                L.u[0] = cvtpk(xA.x - __uint_as_float(H.u[0] << 16),
                               xA.y - __uint_as_float(H.u[0] & 0xFFFF0000u));
                L.u[1] = cvtpk(xA.z - __uint_as_float(H.u[1] << 16),
                               xA.w - __uint_as_float(H.u[1] & 0xFFFF0000u));
                L.u[2] = cvtpk(xB.x - __uint_as_float(H.u[2] << 16),
                               xB.y - __uint_as_float(H.u[2] & 0xFFFF0000u));
                L.u[3] = cvtpk(xB.z - __uint_as_float(H.u[3] << 16),
                               xB.w - __uint_as_float(H.u[3] & 0xFFFF0000u));
                BxH = H.s; BxL = L.s;
            }
            // prefetch x(it+1), clamped
            {
                const int tn = (it < SEQ - 1) ? it + 1 : SEQ - 1;
                const float* p = xp + (size_t)tn * IN;
                xA = *(const float4*)p;
                xB = (lg < 3) ? *(const float4*)(p + 4) : make_float4(0.f, 0.f, 0.f, 0.f);
            }

            f32x4 accx = {biasv[0], biasv[1], biasv[2], biasv[3]};
            accx = mfma_bf(WxH, BxH, accx);
            accx = mfma_bf(WxL, BxH, accx);
            accx = mfma_bf(WxH, BxL, accx);

            i32x4 aa = mfma_i8(Wa[0][0], Ba0[0], z4);
            aa = mfma_i8(Wa[0][1], Ba0[1], aa);
            i32x4 cr = mfma_i8(Wb[0][0], Ba0[0], z4);
            cr = mfma_i8(Wb[0][1], Ba0[1], cr);

            float t0 = fast_tanh(accx[0] + SH_AA * fmaf((float)cr[0], 1.0f / 256.0f, (float)aa[0]));
            float t1 = fast_tanh(accx[1] + SH_AA * fmaf((float)cr[1], 1.0f / 256.0f, (float)aa[1]));
            float t2 = fast_tanh(accx[2] + SH_AA * fmaf((float)cr[2], 1.0f / 256.0f, (float)aa[2]));
            float t3 = fast_tanh(accx[3] + SH_AA * fmaf((float)cr[3], 1.0f / 256.0f, (float)aa[3]));
            *(unsigned*)&hmem[0][wr][wbase] = quant4a(t0, t1, t2, t3);
        } else {
            i32x4 Ba0[2], Ba1[2];
            Ba0[0] = *(const i32x4*)&hmem[0][rd][rbase];
            Ba0[1] = *(const i32x4*)&hmem[0][rd][rbase + 64];
            Ba1[0] = *(const i32x4*)&hmem[1][rd][rbase];
            Ba1[1] = *(const i32x4*)&hmem[1][rd][rbase + 64];

            i32x4 aa = mfma_i8(Wa[0][0], Ba0[0], z4);
            aa = mfma_i8(Wa[0][1], Ba0[1], aa);
            aa = mfma_i8(Wa[1][0], Ba1[0], aa);
            aa = mfma_i8(Wa[1][1], Ba1[1], aa);
            i32x4 cr = mfma_i8(Wb[0][0], Ba0[0], z4);
            cr = mfma_i8(Wb[0][1], Ba0[1], cr);
            cr = mfma_i8(Wb[1][0], Ba1[0], cr);
            cr = mfma_i8(Wb[1][1], Ba1[1], cr);

            float t0, t1, t2, t3;
            if (it == 0) {
                t0 = t1 = t2 = t3 = 0.0f;
            } else {
                t0 = fast_tanh(biasv[0] + SH_AA * fmaf((float)cr[0], 1.0f / 256.0f, (float)aa[0]));
                t1 = fast_tanh(biasv[1] + SH_AA * fmaf((float)cr[1], 1.0f / 256.0f, (float)aa[1]));
                t2 = fast_tanh(biasv[2] + SH_AA * fmaf((float)cr[2], 1.0f / 256.0f, (float)aa[2]));
                t3 = fast_tanh(biasv[3] + SH_AA * fmaf((float)cr[3], 1.0f / 256.0f, (float)aa[3]));
            }
            *(unsigned*)&hmem[1][wr][wbase] = quant4a(t0, t1, t2, t3);
            if (it == SEQ) {   // exact f32 h1(511) for the fc
                const int u = 16 * T + 4 * lg;
                hfin[lm][u + 0] = t0;
                hfin[lm][u + 1] = t1;
                hfin[lm][u + 2] = t2;
                hfin[lm][u + 3] = t3;
            }
        }
        __syncthreads();
    }

    // ---- fc from exact f32 h1(511)
    if (t < MB * NCLS) {
        const int r = t / NCLS, c = t % NCLS;
        float acc = b_fc[c];
        const float* hf = &hfin[r][0];
        #pragma unroll 4
        for (int k = 0; k < HID; ++k)
            acc = fmaf(W_fc[c * HID + k], hf[k], acc);
        out[(b0 + r) * NCLS + c] = acc;
    }
}

extern "C" void kernel_launch(void* const* d_in, const int* in_sizes, int n_in,
                              void* d_out, int out_size, void* d_ws, size_t ws_size,
                              hipStream_t stream) {
    const float* x     = (const float*)d_in[0];
    const float* W_ih0 = (const float*)d_in[1];
    const float* W_hh0 = (const float*)d_in[2];
    const float* b_ih0 = (const float*)d_in[3];
    const float* b_hh0 = (const float*)d_in[4];
    const float* W_ih1 = (const float*)d_in[5];
    const float* W_hh1 = (const float*)d_in[6];
    const float* b_ih1 = (const float*)d_in[7];
    const float* b_hh1 = (const float*)d_in[8];
    const float* W_fc  = (const float*)d_in[9];
    const float* b_fc  = (const float*)d_in[10];
    float* out = (float*)d_out;

    rnn2_i8t<<<dim3(512 / MB), dim3(1024), 0, stream>>>(
        x, W_ih0, W_hh0, b_ih0, b_hh0, W_ih1, W_hh1, b_ih1, b_hh1, W_fc, b_fc, out);
}